// Round 13
// baseline (99.533 us; speedup 1.0000x reference)
//
#include <hip/hip_runtime.h>
#include <stdint.h>

#define N_ROWS  8192
#define DIM     512            // elements = bytes (fp8)
#define BM      256            // tile M = N = 256
#define BK      64             // K-bytes per tile
#define NTT     8              // K-tiles per super-tile (DIM/BK)
#define NST     4              // super-tiles (by values) per block
#define NG      (NTT * NST)    // 32 flat tiles per block
#define NBUF    4              // LDS ring buffers
#define TB      (BM * BK)      // 16 KB per tile side
#define NCB     32             // j-blocks (8192/256)
#define THREADS 1024           // 16 waves = 4 waves/SIMD (TLP experiment)
#define SCL16   0x7B7B7B7BU    // e8m0 123 = 2^-4 per operand (undoes data x16)

typedef __attribute__((ext_vector_type(16))) float f32x16;
typedef __attribute__((ext_vector_type(8)))  int   i32x8;

#define BAR()    { asm volatile("" ::: "memory"); __builtin_amdgcn_s_barrier(); asm volatile("" ::: "memory"); }
#define WAITV(n) asm volatile("s_waitcnt vmcnt(" #n ")" ::: "memory")
#define WAITL0() asm volatile("s_waitcnt lgkmcnt(0)" ::: "memory")

#define MFMA8(a, b, c) __builtin_amdgcn_mfma_scale_f32_32x32x64_f8f6f4( \
    (a), (b), (c), 0, 0, 0, SCL16, 0, SCL16)

// manual RNE float -> OCP e4m3fn (|f| <= 16 guaranteed; no NaN/inf inputs)
__device__ __forceinline__ unsigned int f2e4m3(float f) {
    unsigned int u = __float_as_uint(f);
    unsigned int s = (u >> 24) & 0x80u;
    float a = fabsf(f);
    if (a < 0.015625f) {                     // subnormal: step 2^-9
        int q = (int)rintf(a * 512.0f);      // 0..8 (8 rolls into min-normal)
        return s | (unsigned int)q;
    }
    unsigned int mag = u & 0x7fffffffu;
    mag += 0x7FFFFu + ((mag >> 20) & 1u);    // RNE into 3-bit mantissa
    return s | ((mag >> 20) - 960u);         // (E-120)<<3 | M3
}

// async global -> LDS, 16 B per lane (wave-uniform LDS base + lane*16)
__device__ __forceinline__ void gload_lds16(const void* g, void* l) {
    __builtin_amdgcn_global_load_lds(
        (const __attribute__((address_space(1))) unsigned int*)g,
        (__attribute__((address_space(3))) unsigned int*)l,
        16, 0, 0);
}

// ---------------- Kernel 1: L2-normalize rows + cast to fp8 (x16) ----------
__global__ __launch_bounds__(256) void norm_cast_kernel(
    const float* __restrict__ z1, const float* __restrict__ z2,
    unsigned char* __restrict__ o1, unsigned char* __restrict__ o2)
{
    int row  = blockIdx.x * 4 + (threadIdx.x >> 6);
    int lane = threadIdx.x & 63;
    const float* src;
    unsigned char* dst;
    if (row < N_ROWS) { src = z1 + (size_t)row * DIM;            dst = o1 + (size_t)row * DIM; }
    else              { src = z2 + (size_t)(row - N_ROWS) * DIM; dst = o2 + (size_t)(row - N_ROWS) * DIM; }

    const float4* s4 = (const float4*)src + lane * 2;
    float4 a = s4[0], b = s4[1];
    float ss = a.x*a.x + a.y*a.y + a.z*a.z + a.w*a.w
             + b.x*b.x + b.y*b.y + b.z*b.z + b.w*b.w;
#pragma unroll
    for (int x = 1; x < 64; x <<= 1) ss += __shfl_xor(ss, x);
    float inv = 16.0f / fmaxf(sqrtf(ss), 1e-12f);   // x16 into e4m3 normal range

    uint2 o;
    o.x = f2e4m3(a.x*inv) | (f2e4m3(a.y*inv) << 8) | (f2e4m3(a.z*inv) << 16) | (f2e4m3(a.w*inv) << 24);
    o.y = f2e4m3(b.x*inv) | (f2e4m3(b.y*inv) << 8) | (f2e4m3(b.z*inv) << 16) | (f2e4m3(b.w*inv) << 24);
    *(uint2*)(dst + lane * 8) = o;
}

// ---------------- Kernel 2: persistent 256x256 MX-fp8, 16 waves ------------
// TLP experiment: 16 waves (4/SIMD) on the SAME persistent 256x256 ring
// structure. Wave = 64j x 64i -> 4 MFMA/tile. J-frags double-buffered in
// regs (read t+1 during t); I-frags read at tile start (TLP hides lgkm).
// Stage prefetch distance 3 tiles; counted WAITV(2) at tile start (never 0
// until tail). One barrier per tile.
__global__ __launch_bounds__(THREADS) void fused_sim_kernel(
    const unsigned char* __restrict__ A,    // z1 fp8 [8192][512]
    const unsigned char* __restrict__ B,    // z2 fp8 [8192][512]
    const int* __restrict__ ids,
    float* __restrict__ partial)            // [3][NCB][N_ROWS]
{
    __shared__ alignas(128) unsigned char Js[NBUF][TB];   // 64 KB (J = z2)
    __shared__ alignas(128) unsigned char Is[NBUF][TB];   // 64 KB (I = z1)
    __shared__ int   idj[BM];                             // 1 KB
    __shared__ float red[4][3][BM];                       // 12 KB

    const int tid  = threadIdx.x;
    const int lane = tid & 63;
    const int wid  = tid >> 6;                 // 0..15
    const int wr   = wid >> 2;                 // 0..3  (j quarter: 64 rows)
    const int wc   = wid & 3;                  // 0..3  (i quarter: 64 rows)
    const int li   = lane & 31, lh = lane >> 5;

    // XCD chunking: each XCD owns a 4-wide bx stripe (its z2 slice L2-hot)
    const int flat = blockIdx.x;               // 256 blocks
    const int xcd  = flat & 7;
    const int s    = flat >> 3;                // 0..31
    const int bx   = xcd * 4 + (s & 3);        // 0..31  (j block, fixed)
    const int byg  = s >> 2;                   // 0..7   (i group; 4 by's each)
    const int bcol = bx * BM;

    // ids: per-thread rids (uniform count) + idj -> LDS (divergent, oldest)
    int rid0 = ids[(size_t)(byg * 4 + 0) * BM + wc * 64 + li];
    int rid1 = ids[(size_t)(byg * 4 + 0) * BM + wc * 64 + 32 + li];
    if (tid < BM) idj[tid] = ids[bcol + tid];

    // stage tile g (16 KB/side, 1 instr/thread/side with 1024 threads):
    // seg=tid -> f=seg>>7, lanef=(seg&127)>>1, half=seg&1; LDS addr=seg*16
    // global row = f*32 + (lanef&31), kbyte = (lanef>>5)*32 + half*16
    auto stageJ = [&](int g) {
        const int buf = g & 3, k0 = (g & 7) * BK;
        int lf = (tid & 127) >> 1, half = tid & 1;
        int row = (tid >> 7) * 32 + (lf & 31);
        int kb  = (lf >> 5) * 32 + half * 16;
        gload_lds16(B + (size_t)(bcol + row) * DIM + k0 + kb, &Js[buf][tid * 16]);
    };
    auto stageI = [&](int g) {
        const int buf = g & 3, k0 = (g & 7) * BK;
        const int brow = (byg * 4 + (g >> 3)) * BM;
        int lf = (tid & 127) >> 1, half = tid & 1;
        int row = (tid >> 7) * 32 + (lf & 31);
        int kb  = (lf >> 5) * 32 + half * 16;
        gload_lds16(A + (size_t)(brow + row) * DIM + k0 + kb, &Is[buf][tid * 16]);
    };

    // frag reads: lane-contiguous 32 B (operand row = lane&31,
    // k-bytes = (lane>>5)*32) — direct i32x8 (r6/r12 layout)
    auto ldJ = [&](int buf, int jb) -> i32x8 {
        return *(const i32x8*)&Js[buf][((wr * 2 + jb) * 64 + lane) * 32];
    };
    auto ldI = [&](int buf, int ib) -> i32x8 {
        return *(const i32x8*)&Is[buf][((wc * 2 + ib) * 64 + lane) * 32];
    };

    f32x16 acc[2][2];
#pragma unroll
    for (int m = 0; m < 2; ++m)
#pragma unroll
        for (int n = 0; n < 2; ++n) acc[m][n] = (f32x16)0.f;

    i32x8 jf[2][2];

    // prologue: stage tiles 0,1,2 (6 instr incl. per-side); drain 0,1
    stageI(0); stageJ(0);
    stageI(1); stageJ(1);
    stageI(2); stageJ(2);
    WAITL0();                      // idj ds_write flushed before BAR
    WAITV(2);                      // tiles 0,1 + ids drained; tile2 in flight
    BAR();
    jf[0][0] = ldJ(0, 0); jf[0][1] = ldJ(0, 1);   // tile 0's J-frags

#pragma unroll
    for (int st = 0; st < NST; ++st) {
#pragma unroll
        for (int t = 0; t < NTT; ++t) {
            const int g = st * NTT + t;
            const int p = g & 1, q = p ^ 1;
            const int cur = g & 3;

            // counted start-of-tile wait: drain tile g+1's stages,
            // keep tile g+2's in flight (never 0 until tail)
            if (g <= NG - 3) { WAITV(2); } else { WAITV(0); }
            BAR();
            i32x8 i0 = ldI(cur, 0), i1 = ldI(cur, 1);       // tile g's I
            if (g + 1 < NG) {                               // tile g+1's J
                jf[q][0] = ldJ((g + 1) & 3, 0);
                jf[q][1] = ldJ((g + 1) & 3, 1);
            }
            if (g + 3 < NG) { stageI(g + 3); stageJ(g + 3); }
            __builtin_amdgcn_s_setprio(1);
            acc[0][0] = MFMA8(jf[p][0], i0, acc[0][0]);
            acc[0][1] = MFMA8(jf[p][0], i1, acc[0][1]);
            acc[1][0] = MFMA8(jf[p][1], i0, acc[1][0]);
            acc[1][1] = MFMA8(jf[p][1], i1, acc[1][1]);
            __builtin_amdgcn_s_setprio(0);
        }

        // ---- per-super-tile epilogue (prefetches for next st keep flying)
        // 32x32 C/D: col(i)=lane&31, row(j)=(reg&3)+8*(reg>>2)+4*(lane>>5)
        const int brow = (byg * 4 + st) * BM;
        float dp0 = 0.f, sp0 = 0.f, qp0 = 0.f, dp1 = 0.f, sp1 = 0.f, qp1 = 0.f;
#pragma unroll
        for (int jb = 0; jb < 2; ++jb) {
#pragma unroll
            for (int reg = 0; reg < 16; ++reg) {
                int j   = wr * 64 + jb * 32 + (reg & 3) + 8 * (reg >> 2) + 4 * lh;
                int cid = idj[j];
                float v0 = acc[jb][0][reg], v1 = acc[jb][1][reg];
                float e0 = __expf(v0 * 10.0f - 10.0f);   // exp(sim - 10)
                float e1 = __expf(v1 * 10.0f - 10.0f);
                dp0 += e0; dp1 += e1;
                sp0 += (rid0 == cid) ? e0 : 0.f;  qp0 += (rid0 == cid) ? 0.f : e0 * e0;
                sp1 += (rid1 == cid) ? e1 : 0.f;  qp1 += (rid1 == cid) ? 0.f : e1 * e1;
            }
        }
        dp0 += __shfl_xor(dp0, 32); sp0 += __shfl_xor(sp0, 32); qp0 += __shfl_xor(qp0, 32);
        dp1 += __shfl_xor(dp1, 32); sp1 += __shfl_xor(sp1, 32); qp1 += __shfl_xor(qp1, 32);
        if (lane < 32) {
            red[wr][0][wc * 64 + li]      = dp0;
            red[wr][1][wc * 64 + li]      = sp0;
            red[wr][2][wc * 64 + li]      = qp0;
            red[wr][0][wc * 64 + 32 + li] = dp1;
            red[wr][1][wc * 64 + 32 + li] = sp1;
            red[wr][2][wc * 64 + 32 + li] = qp1;
        }
        WAITL0();
        BAR();
        if (tid < BM) {
#pragma unroll
            for (int s2 = 0; s2 < 3; ++s2) {
                float v = red[0][s2][tid] + red[1][s2][tid]
                        + red[2][s2][tid] + red[3][s2][tid];
                partial[((size_t)s2 * NCB + bx) * N_ROWS + brow + tid] = v;
            }
        }
        if (st + 1 < NST) {
            rid0 = ids[(size_t)(byg * 4 + st + 1) * BM + wc * 64 + li];
            rid1 = ids[(size_t)(byg * 4 + st + 1) * BM + wc * 64 + 32 + li];
#pragma unroll
            for (int m = 0; m < 2; ++m)
#pragma unroll
                for (int n = 0; n < 2; ++n) acc[m][n] = (f32x16)0.f;
        }
    }
}

// ---------------- Kernel 3: per-row loss, per-block sums ----------------
__global__ __launch_bounds__(256) void reduce_kernel(
    const float* __restrict__ partial, float* __restrict__ blocksum)
{
    int row = blockIdx.x * 256 + threadIdx.x;
    float den = 0.f, sm = 0.f, sq = 0.f;
#pragma unroll 4
    for (int cb = 0; cb < NCB; ++cb) {
        den += partial[((size_t)0 * NCB + cb) * N_ROWS + row];
        sm  += partial[((size_t)1 * NCB + cb) * N_ROWS + row];
        sq  += partial[((size_t)2 * NCB + cb) * N_ROWS + row];
    }
    float num  = sm + sq / den;
    float loss = -logf(num / (den + 1e-8f) + 1e-8f);
#pragma unroll
    for (int x = 1; x < 64; x <<= 1) loss += __shfl_xor(loss, x);
    __shared__ float p[4];
    if ((threadIdx.x & 63) == 0) p[threadIdx.x >> 6] = loss;
    __syncthreads();
    if (threadIdx.x == 0) blocksum[blockIdx.x] = p[0] + p[1] + p[2] + p[3];
}

__global__ void final_kernel(const float* __restrict__ blocksum, float* __restrict__ out)
{
    float v = (threadIdx.x < 32) ? blocksum[threadIdx.x] : 0.f;
#pragma unroll
    for (int x = 1; x < 64; x <<= 1) v += __shfl_xor(v, x);
    if (threadIdx.x == 0) out[0] = v * (1.0f / (float)N_ROWS);
}

extern "C" void kernel_launch(void* const* d_in, const int* in_sizes, int n_in,
                              void* d_out, int out_size, void* d_ws, size_t ws_size,
                              hipStream_t stream) {
    const float* z1  = (const float*)d_in[0];
    const float* z2  = (const float*)d_in[1];
    const int*   ids = (const int*)d_in[2];

    char* ws = (char*)d_ws;
    unsigned char* z1q = (unsigned char*)ws;                                 // 4 MB
    unsigned char* z2q = (unsigned char*)(ws + (size_t)N_ROWS * DIM);        // 4 MB
    float* partial  = (float*)(ws + (size_t)2 * N_ROWS * DIM);               // 3 MB
    float* blocksum = partial + (size_t)3 * NCB * N_ROWS;                    // 128 B

    norm_cast_kernel<<<dim3(4096), dim3(256), 0, stream>>>(z1, z2, z1q, z2q);
    fused_sim_kernel<<<dim3(256), dim3(THREADS), 0, stream>>>(z1q, z2q, ids, partial);
    reduce_kernel<<<dim3(32), dim3(256), 0, stream>>>(partial, blocksum);
    final_kernel<<<dim3(1), dim3(64), 0, stream>>>(blocksum, (float*)d_out);
}